// Round 4
// baseline (225.292 us; speedup 1.0000x reference)
//
#include <hip/hip_runtime.h>
#include <hip/hip_bf16.h>
#include <cstdint>

typedef _Float16 f16;
typedef _Float16 f16x4 __attribute__((ext_vector_type(4)));
typedef _Float16 f16x8 __attribute__((ext_vector_type(8)));
typedef float f32x4 __attribute__((ext_vector_type(4)));

#define LNEG (-1e30f)

__device__ __forceinline__ f32x4 mfma16(f16x8 a, f16x8 b, f32x4 c){
    return __builtin_amdgcn_mfma_f32_16x16x32_f16(a, b, c, 0, 0, 0);
}

__device__ __forceinline__ void gload16(const void* g, void* l){
    __builtin_amdgcn_global_load_lds((const __attribute__((address_space(1))) void*)g,
                                     (__attribute__((address_space(3))) void*)l,
                                     16, 0, 0);
}

// ---------- fused f32 -> f16 convert for x + 4 weights (contiguous dst) ----------
__global__ __launch_bounds__(256) void cvt5(
    const float* __restrict__ x,  const float* __restrict__ wq,
    const float* __restrict__ wk, const float* __restrict__ wv,
    const float* __restrict__ wp, f16* __restrict__ dst, int nx4, int nw4)
{
    int i = blockIdx.x * blockDim.x + threadIdx.x;
    const float* src; int off;
    if (i < nx4){ src = x; off = i; }
    else {
        int j = i - nx4;
        int s = j >> 18;
        off = j & (nw4 - 1);
        src = (s == 0) ? wq : (s == 1) ? wk : (s == 2) ? wv : wp;
    }
    float4 v = ((const float4*)src)[off];
    f16x4 o = { (f16)v.x, (f16)v.y, (f16)v.z, (f16)v.w };
    *(f16x4*)&dst[(size_t)i * 4] = o;
}

// ---------- GEMM (m97 recipe): out[m][n] = sum_k A[m][k] * W[n][k] ----------
template<typename OutT>
__global__ __launch_bounds__(256) void gemm_m97(
    const f16* __restrict__ A, const f16* __restrict__ W0, size_t wstride,
    OutT* __restrict__ out0, size_t ostride, int M, int N, int K)
{
    const int tid  = threadIdx.x;
    const int lane = tid & 63;
    const int w    = tid >> 6;
    const int g    = lane >> 4;
    const int wr   = w >> 1, wc = w & 1;
    const int m0   = blockIdx.y * 128;
    const int n0   = blockIdx.x * 128;
    const f16* Wz  = W0 + wstride * blockIdx.z;
    OutT* out      = out0 + ostride * blockIdx.z;

    __shared__ f16 At[128 * 64];
    __shared__ f16 Bt[128 * 64];

    f32x4 acc[4][4] = {};

    const int lrow = lane >> 3;
    const int lcol = (lane & 7) * 8;

    for (int k0 = 0; k0 < K; k0 += 64){
        #pragma unroll
        for (int j = 0; j < 4; ++j){
            const int c   = w * 4 + j;
            const int row = c * 8 + lrow;
            gload16(&A [(size_t)(m0 + row) * K + k0 + lcol], &At[c * 512]);
            gload16(&Wz[(size_t)(n0 + row) * K + k0 + lcol], &Bt[c * 512]);
        }
        __syncthreads();
        #pragma unroll
        for (int kk = 0; kk < 2; ++kk){
            f16x8 af[4], bf[4];
            #pragma unroll
            for (int mf = 0; mf < 4; ++mf){
                int row = wr * 64 + mf * 16 + (lane & 15);
                af[mf] = *(const f16x8*)((const char*)At + row * 128 + kk * 64 + 16 * g);
            }
            #pragma unroll
            for (int nf = 0; nf < 4; ++nf){
                int row = wc * 64 + nf * 16 + (lane & 15);
                bf[nf] = *(const f16x8*)((const char*)Bt + row * 128 + kk * 64 + 16 * g);
            }
            #pragma unroll
            for (int mf = 0; mf < 4; ++mf)
                #pragma unroll
                for (int nf = 0; nf < 4; ++nf)
                    acc[mf][nf] = mfma16(af[mf], bf[nf], acc[mf][nf]);
        }
        __syncthreads();
    }
    #pragma unroll
    for (int mf = 0; mf < 4; ++mf)
        #pragma unroll
        for (int nf = 0; nf < 4; ++nf)
            #pragma unroll
            for (int r = 0; r < 4; ++r){
                int row = m0 + wr * 64 + mf * 16 + 4 * (lane >> 4) + r;
                int col = n0 + wc * 64 + nf * 16 + (lane & 15);
                out[(size_t)row * N + col] = (OutT)acc[mf][nf][r];
            }
}

// ---------- V (B,L,H,D) -> V^T (B*H, D=64, L=2048) ----------
__global__ __launch_bounds__(256) void transpose_v(const f16* __restrict__ v, f16* __restrict__ vt){
    const int t  = threadIdx.x;
    const int lt = blockIdx.x;
    const int bh = blockIdx.y;
    const int b  = bh >> 4, h = bh & 15;
    const int l0 = lt * 64;
    __shared__ f16 tile[64][72];
    #pragma unroll
    for (int r = 0; r < 2; ++r){
        int i  = t / 8 + 32 * r;
        int jb = t % 8;
        f16x8 vv = *(const f16x8*)&v[(size_t)(b * 2048 + l0 + i) * 1024 + h * 64 + jb * 8];
        *(f16x8*)&tile[i][jb * 8] = vv;
    }
    __syncthreads();
    #pragma unroll
    for (int r = 0; r < 2; ++r){
        int d  = t / 8 + 32 * r;
        int lb = t % 8;
        f16x8 o;
        #pragma unroll
        for (int q2 = 0; q2 < 8; ++q2) o[q2] = tile[lb * 8 + q2][d];
        *(f16x8*)&vt[(size_t)(bh * 64 + d) * 2048 + l0 + lb * 8] = o;
    }
}

// ---------- fused causal flash attention ----------
// Barrier-free: K and V^T fragments read directly from global (L1/L2-resident:
// 256KB per head); LDS holds only the per-wave P tile. Waves run independently.
__global__ __launch_bounds__(256, 4) void attn_fused(
    const f16* __restrict__ q, const f16* __restrict__ k,
    const f16* __restrict__ vt, const int* __restrict__ amask,
    f16* __restrict__ y)
{
    const int tid  = threadIdx.x;
    const int lane = tid & 63;
    const int w    = tid >> 6;
    const int g    = lane >> 4;
    const int qq   = lane & 15;

    // work-balance swizzle (round-1 proven): co-resident blocks pair qt, 31-qt
    const int lin = blockIdx.x;
    const int jj = lin >> 8, ii = lin & 255;
    const int qt = (jj & 1) ? (31 - (ii & 31)) : (ii & 31);
    const int bh = (ii >> 5) | (jj << 3);
    const int b = bh >> 4, h = bh & 15;
    const int q0w = qt * 64 + w * 16;
    const int nkt = qt + 1;

    __shared__ char sP[4][16 * 128];   // per-wave P [q][key], XOR-swizzled

    const f16* kbase = k  + ((size_t)b * 2048) * 1024 + h * 64;
    const f16* vtb   = vt + (size_t)bh * 64 * 2048;

    // Q pre-scaled by (1/sqrt(64)) * log2(e): softmax in exp2 space
    const f16 qscale = (f16)(0.125f * 1.44269504088896f);
    f16x8 aq[2];
    #pragma unroll
    for (int f = 0; f < 2; ++f){
        aq[f] = *(const f16x8*)&q[((size_t)(b * 2048 + q0w + qq)) * 1024 + h * 64 + f * 32 + 8 * g];
        #pragma unroll
        for (int j = 0; j < 8; ++j) aq[f][j] *= qscale;
    }

    f32x4 acc_o[4] = {};
    float m_ln = LNEG, l_ln = 0.f;

    char* pbase = sP[w] + qq * 128;
    const int swp = (qq & 7) << 4;

    for (int kt = 0; kt < nkt; ++kt){
        const int k0 = kt * 64;

        unsigned long long tokbits = __ballot(amask[b * 2048 + k0 + lane] != 0);
        const bool tokall = (tokbits == ~0ull);

        // QK^T swapped: A = K rows direct from global (L1/L2), B = Q (regs)
        f32x4 acc_s[4] = {};
        #pragma unroll
        for (int kf = 0; kf < 4; ++kf){
            const f16* kr = kbase + (size_t)(k0 + kf * 16 + qq) * 1024;
            #pragma unroll
            for (int f = 0; f < 2; ++f){
                f16x8 ak = *(const f16x8*)(kr + f * 32 + 8 * g);
                acc_s[kf] = mfma16(ak, aq[f], acc_s[kf]);
            }
        }

        const bool fullt = (k0 + 63 <= q0w) && tokall;
        float sv[16];
        #pragma unroll
        for (int kf = 0; kf < 4; ++kf)
            #pragma unroll
            for (int r = 0; r < 4; ++r){
                float s = acc_s[kf][r];
                if (!fullt){
                    const int keyl = kf * 16 + 4 * g + r;
                    const bool ok = (k0 + keyl <= q0w + qq) && ((tokbits >> keyl) & 1);
                    s = ok ? s : LNEG;
                }
                sv[kf * 4 + r] = s;
            }

        float tmax = sv[0];
        #pragma unroll
        for (int i = 1; i < 16; ++i) tmax = fmaxf(tmax, sv[i]);
        tmax = fmaxf(tmax, __shfl_xor(tmax, 16));
        tmax = fmaxf(tmax, __shfl_xor(tmax, 32));
        const bool skip = __all(tmax <= m_ln + 8.f);   // defer-max (log2 units)
        float alpha = 1.f;
        if (!skip){
            const float newm = fmaxf(m_ln, tmax);
            alpha = exp2f(m_ln - newm);
            m_ln = newm;
        }
        float rs = 0.f;
        #pragma unroll
        for (int i = 0; i < 16; ++i){ sv[i] = exp2f(sv[i] - m_ln); rs += sv[i]; }
        rs += __shfl_xor(rs, 16);
        rs += __shfl_xor(rs, 32);
        l_ln = l_ln * alpha + rs;
        if (!skip){
            #pragma unroll
            for (int r = 0; r < 4; ++r){
                const float ar = __shfl(alpha, 4 * g + r);
                #pragma unroll
                for (int nf = 0; nf < 4; ++nf) acc_o[nf][r] *= ar;
            }
        }

        #pragma unroll
        for (int kf = 0; kf < 4; ++kf){
            f16x4 pk = { (f16)sv[kf*4+0], (f16)sv[kf*4+1], (f16)sv[kf*4+2], (f16)sv[kf*4+3] };
            *(f16x4*)(pbase + ((kf * 32 + 8 * g) ^ swp)) = pk;
        }
        __builtin_amdgcn_wave_barrier();

        // PV: A = P (per-wave LDS), B = V^T rows direct from global
        #pragma unroll
        for (int f = 0; f < 2; ++f){
            f16x8 ap = *(const f16x8*)(pbase + ((f * 64 + 16 * g) ^ swp));
            #pragma unroll
            for (int nf = 0; nf < 4; ++nf){
                f16x8 bv = *(const f16x8*)(vtb + (size_t)(nf * 16 + qq) * 2048 + k0 + f * 32 + 8 * g);
                acc_o[nf] = mfma16(ap, bv, acc_o[nf]);
            }
        }
        __builtin_amdgcn_wave_barrier();   // P overwritten next iteration
    }

    const float invl = 1.f / l_ln;
    #pragma unroll
    for (int r = 0; r < 4; ++r){
        const float ir = __shfl(invl, 4 * g + r);
        const int row = q0w + 4 * g + r;
        #pragma unroll
        for (int nf = 0; nf < 4; ++nf)
            y[((size_t)(b * 2048 + row)) * 1024 + h * 64 + nf * 16 + qq] = (f16)(acc_o[nf][r] * ir);
    }
}

extern "C" void kernel_launch(void* const* d_in, const int* in_sizes, int n_in,
                              void* d_out, int out_size, void* d_ws, size_t ws_size,
                              hipStream_t stream){
    const float* x  = (const float*)d_in[0];
    const int*   am = (const int*)d_in[1];
    const float* Wq = (const float*)d_in[2];
    const float* Wk = (const float*)d_in[3];
    const float* Wv = (const float*)d_in[4];
    const float* Wp = (const float*)d_in[5];
    float* out = (float*)d_out;

    char* ws = (char*)d_ws;
    const size_t XE = (size_t)4096 * 1024;
    const size_t WE = (size_t)1024 * 1024;

    f16* x16 = (f16*)(ws);
    f16* w16 = (f16*)(ws + XE * 2);
    f16* qkv = (f16*)(ws + XE * 2 + WE * 8);
    f16* vt  = (f16*)(ws + XE * 2 + WE * 8 + XE * 6);
    f16* y16 = (f16*)(ws + XE * 2 + WE * 8 + XE * 8);

    cvt5<<<8192, 256, 0, stream>>>(x, Wq, Wk, Wv, Wp, x16,
                                   (int)(XE / 4), (int)(WE / 4));

    gemm_m97<f16><<<dim3(8, 32, 3), 256, 0, stream>>>(x16, w16, WE, qkv, XE, 4096, 1024, 1024);

    transpose_v<<<dim3(32, 32), 256, 0, stream>>>(qkv + 2 * XE, vt);

    attn_fused<<<dim3(1024), 256, 0, stream>>>(qkv, qkv + XE, vt, am, y16);

    gemm_m97<float><<<dim3(8, 32, 1), 256, 0, stream>>>(y16, w16 + 3 * WE, 0, out, 0, 4096, 1024, 1024);
}

// Round 7
// 126.644 us; speedup vs baseline: 1.7789x; 1.7789x over previous
//
#include <hip/hip_runtime.h>
#include <hip/hip_bf16.h>
#include <cstdint>

typedef _Float16 f16;
typedef _Float16 f16x4 __attribute__((ext_vector_type(4)));
typedef _Float16 f16x8 __attribute__((ext_vector_type(8)));
typedef float f32x4 __attribute__((ext_vector_type(4)));

#define LNEG (-1e30f)

__device__ __forceinline__ f32x4 mfma16(f16x8 a, f16x8 b, f32x4 c){
    return __builtin_amdgcn_mfma_f32_16x16x32_f16(a, b, c, 0, 0, 0);
}

// ---------- fused f32 -> f16 convert for x + 4 weights (contiguous dst) ----------
__global__ __launch_bounds__(256) void cvt5(
    const float* __restrict__ x,  const float* __restrict__ wq,
    const float* __restrict__ wk, const float* __restrict__ wv,
    const float* __restrict__ wp, f16* __restrict__ dst, int nx4, int nw4)
{
    int i = blockIdx.x * blockDim.x + threadIdx.x;
    const float* src; int off;
    if (i < nx4){ src = x; off = i; }
    else {
        int j = i - nx4;
        int s = j >> 18;              // nw4 == 2^18
        off = j & (nw4 - 1);
        src = (s == 0) ? wq : (s == 1) ? wk : (s == 2) ? wv : wp;
    }
    float4 v = ((const float4*)src)[off];
    f16x4 o = { (f16)v.x, (f16)v.y, (f16)v.z, (f16)v.w };
    *(f16x4*)&dst[(size_t)i * 4] = o;
}

// ---------- GEMM: reg-staged, XOR-swizzled LDS, double-buffered, 1 barrier/K-step ----------
// out[m][n] = sum_k A[m][k] * W[n][k]. 128x128 tile, BK=64, 4 waves.
// Next-tile global loads issue BEFORE this tile's MFMAs (latency hides under
// compute); LDS writes go to the other buffer; single __syncthreads per step
// fences both "nb writes visible" and "cur reads done before next overwrite".
template<typename OutT>
__global__ __launch_bounds__(256) void gemm_xwt(
    const f16* __restrict__ A, const f16* __restrict__ W0, size_t wstride,
    OutT* __restrict__ out0, size_t ostride, int M, int N, int K)
{
    const int tid  = threadIdx.x;
    const int lane = tid & 63;
    const int w    = tid >> 6;
    const int wr   = w >> 1, wc = w & 1;
    const int m0   = blockIdx.y * 128;
    const int n0   = blockIdx.x * 128;
    const f16* Wz  = W0 + wstride * blockIdx.z;
    OutT* out      = out0 + ostride * blockIdx.z;

    __shared__ f16 At[2][128 * 64];
    __shared__ f16 Bt[2][128 * 64];

    f32x4 acc[4][4] = {};
    f16x8 avr[4], bvr[4];

    // staging geometry: thread covers 4 chunks of 16B in each 16KB tile
    int srow[4], scolb[4], sswz[4];
    #pragma unroll
    for (int j = 0; j < 4; ++j){
        int off  = (j * 256 + tid) * 16;
        srow[j]  = off >> 7;
        scolb[j] = off & 127;
        sswz[j]  = srow[j] * 128 + (scolb[j] ^ ((srow[j] & 7) << 4));
    }

    // prologue: load + store tile 0 into buffer 0
    #pragma unroll
    for (int j = 0; j < 4; ++j){
        avr[j] = *(const f16x8*)&A [(size_t)(m0 + srow[j]) * K + (scolb[j] >> 1)];
        bvr[j] = *(const f16x8*)&Wz[(size_t)(n0 + srow[j]) * K + (scolb[j] >> 1)];
    }
    #pragma unroll
    for (int j = 0; j < 4; ++j){
        *(f16x8*)((char*)At[0] + sswz[j]) = avr[j];
        *(f16x8*)((char*)Bt[0] + sswz[j]) = bvr[j];
    }
    __syncthreads();

    const int NT = K >> 6;
    for (int t = 0; t < NT; ++t){
        const int cur = t & 1;
        const bool pre = (t + 1 < NT);
        if (pre){
            const int k0 = (t + 1) << 6;
            #pragma unroll
            for (int j = 0; j < 4; ++j){
                avr[j] = *(const f16x8*)&A [(size_t)(m0 + srow[j]) * K + k0 + (scolb[j] >> 1)];
                bvr[j] = *(const f16x8*)&Wz[(size_t)(n0 + srow[j]) * K + k0 + (scolb[j] >> 1)];
            }
        }
        #pragma unroll
        for (int kk = 0; kk < 2; ++kk){
            f16x8 af[4], bf[4];
            #pragma unroll
            for (int mf = 0; mf < 4; ++mf){
                int row = wr * 64 + mf * 16 + (lane & 15);
                int cb  = (kk * 64 + 16 * (lane >> 4)) ^ ((row & 7) << 4);
                af[mf] = *(const f16x8*)((const char*)At[cur] + row * 128 + cb);
            }
            #pragma unroll
            for (int nf = 0; nf < 4; ++nf){
                int row = wc * 64 + nf * 16 + (lane & 15);
                int cb  = (kk * 64 + 16 * (lane >> 4)) ^ ((row & 7) << 4);
                bf[nf] = *(const f16x8*)((const char*)Bt[cur] + row * 128 + cb);
            }
            #pragma unroll
            for (int mf = 0; mf < 4; ++mf)
                #pragma unroll
                for (int nf = 0; nf < 4; ++nf)
                    acc[mf][nf] = mfma16(af[mf], bf[nf], acc[mf][nf]);
        }
        if (pre){
            const int nb = cur ^ 1;
            #pragma unroll
            for (int j = 0; j < 4; ++j){
                *(f16x8*)((char*)At[nb] + sswz[j]) = avr[j];
                *(f16x8*)((char*)Bt[nb] + sswz[j]) = bvr[j];
            }
        }
        __syncthreads();
    }
    #pragma unroll
    for (int mf = 0; mf < 4; ++mf)
        #pragma unroll
        for (int nf = 0; nf < 4; ++nf)
            #pragma unroll
            for (int r = 0; r < 4; ++r){
                int row = m0 + wr * 64 + mf * 16 + 4 * (lane >> 4) + r;
                int col = n0 + wc * 64 + nf * 16 + (lane & 15);
                out[(size_t)row * N + col] = (OutT)acc[mf][nf][r];
            }
}

// ---------- V (B,L,H,D) -> V^T (B*H, D=64, L=2048) ----------
__global__ __launch_bounds__(256) void transpose_v(const f16* __restrict__ v, f16* __restrict__ vt){
    const int t  = threadIdx.x;
    const int lt = blockIdx.x;
    const int bh = blockIdx.y;
    const int b  = bh >> 4, h = bh & 15;
    const int l0 = lt * 64;
    __shared__ f16 tile[64][72];
    #pragma unroll
    for (int r = 0; r < 2; ++r){
        int i  = t / 8 + 32 * r;
        int jb = t % 8;
        f16x8 vv = *(const f16x8*)&v[(size_t)(b * 2048 + l0 + i) * 1024 + h * 64 + jb * 8];
        *(f16x8*)&tile[i][jb * 8] = vv;
    }
    __syncthreads();
    #pragma unroll
    for (int r = 0; r < 2; ++r){
        int d  = t / 8 + 32 * r;
        int lb = t % 8;
        f16x8 o;
        #pragma unroll
        for (int q2 = 0; q2 < 8; ++q2) o[q2] = tile[lb * 8 + q2][d];
        *(f16x8*)&vt[(size_t)(bh * 64 + d) * 2048 + l0 + lb * 8] = o;
    }
}

// ---------- fused causal flash attention (round-2 body verbatim; XCD-local remap) ----------
// grid: 1024 blocks, 4 waves; wave owns 16 q-rows. K/V^T staged in LDS
// (double-buffered, XOR-swizzled); per-wave P tile. Co-CU partners (lin,
// lin+256) get trip counts summing to 33; same-head blocks share an XCD.
__global__ __launch_bounds__(256, 4) void attn_fused(
    const f16* __restrict__ q, const f16* __restrict__ k,
    const f16* __restrict__ vt, const int* __restrict__ amask,
    f16* __restrict__ y)
{
    const int tid  = threadIdx.x;
    const int lane = tid & 63;
    const int w    = tid >> 6;
    const int g    = lane >> 4;
    const int qq   = lane & 15;

    // remap: bh from low 5 bits (XCD = lin&7 fixed per head), qt pair-balanced
    const int lin = blockIdx.x;
    const int bh  = ((lin & 7) << 2) | ((lin >> 3) & 3);
    const int qtv = (lin >> 5) & 31;
    const int q5  = (qtv & 7) | ((qtv & 16) >> 1);
    const int qt  = (qtv & 8) ? (31 - q5) : q5;
    const int b = bh >> 4, h = bh & 15;
    const int q0w = qt * 64 + w * 16;
    const int nkt = qt + 1;

    __shared__ char sK[2][64 * 128];
    __shared__ char sV[2][64 * 128];
    __shared__ char sP[4][16 * 128];

    const int srow = (tid * 2) >> 3;
    const int sc8a = (tid * 2) & 7, sc8b = sc8a + 1;
    const int swka = (sc8a * 16) ^ ((srow & 7) << 4);
    const int swkb = (sc8b * 16) ^ ((srow & 7) << 4);
    const f16* kbase  = k  + ((size_t)b * 2048) * 1024 + h * 64;
    const f16* vtbase = vt + (size_t)bh * 64 * 2048;

    const f16 qscale = (f16)(0.125f * 1.44269504088896f);
    f16x8 aq[2];
    #pragma unroll
    for (int f = 0; f < 2; ++f){
        aq[f] = *(const f16x8*)&q[((size_t)(b * 2048 + q0w + qq)) * 1024 + h * 64 + f * 32 + 8 * g];
        #pragma unroll
        for (int j = 0; j < 8; ++j) aq[f][j] *= qscale;
    }

    f32x4 acc_o[4] = {};
    float m_ln = LNEG, l_ln = 0.f;

    char* pbase = sP[w] + qq * 128;
    const int swp = (qq & 7) << 4;

    {
        f16x8 ka  = *(const f16x8*)(kbase  + (size_t)srow * 1024 + sc8a * 8);
        f16x8 kb2 = *(const f16x8*)(kbase  + (size_t)srow * 1024 + sc8b * 8);
        f16x8 va  = *(const f16x8*)(vtbase + (size_t)srow * 2048 + sc8a * 8);
        f16x8 vb  = *(const f16x8*)(vtbase + (size_t)srow * 2048 + sc8b * 8);
        *(f16x8*)(sK[0] + srow * 128 + swka) = ka;
        *(f16x8*)(sK[0] + srow * 128 + swkb) = kb2;
        *(f16x8*)(sV[0] + srow * 128 + swka) = va;
        *(f16x8*)(sV[0] + srow * 128 + swkb) = vb;
    }
    __syncthreads();

    for (int kt = 0; kt < nkt; ++kt){
        const int cur = kt & 1;
        const int k0 = kt * 64;
        const bool pre = (kt + 1 < nkt);

        f16x8 ka, kb2, va, vb;
        if (pre){
            const int nk0 = k0 + 64;
            ka  = *(const f16x8*)(kbase  + (size_t)(nk0 + srow) * 1024 + sc8a * 8);
            kb2 = *(const f16x8*)(kbase  + (size_t)(nk0 + srow) * 1024 + sc8b * 8);
            va  = *(const f16x8*)(vtbase + (size_t)srow * 2048 + nk0 + sc8a * 8);
            vb  = *(const f16x8*)(vtbase + (size_t)srow * 2048 + nk0 + sc8b * 8);
        }

        unsigned long long tokbits = __ballot(amask[b * 2048 + k0 + lane] != 0);
        const bool tokall = (tokbits == ~0ull);

        f32x4 acc_s[4] = {};
        #pragma unroll
        for (int kf = 0; kf < 4; ++kf){
            const int keyl = kf * 16 + qq;
            const char* kr = sK[cur] + keyl * 128;
            const int sw = (keyl & 7) << 4;
            #pragma unroll
            for (int f = 0; f < 2; ++f){
                f16x8 ak = *(const f16x8*)(kr + ((f * 64 + 16 * g) ^ sw));
                acc_s[kf] = mfma16(ak, aq[f], acc_s[kf]);
            }
        }

        const bool fullt = (k0 + 63 <= q0w) && tokall;
        float sv[16];
        #pragma unroll
        for (int kf = 0; kf < 4; ++kf)
            #pragma unroll
            for (int r = 0; r < 4; ++r){
                float s = acc_s[kf][r];
                if (!fullt){
                    const int keyl = kf * 16 + 4 * g + r;
                    const bool ok = (k0 + keyl <= q0w + qq) && ((tokbits >> keyl) & 1);
                    s = ok ? s : LNEG;
                }
                sv[kf * 4 + r] = s;
            }

        float tmax = sv[0];
        #pragma unroll
        for (int i = 1; i < 16; ++i) tmax = fmaxf(tmax, sv[i]);
        tmax = fmaxf(tmax, __shfl_xor(tmax, 16));
        tmax = fmaxf(tmax, __shfl_xor(tmax, 32));
        const bool skip = __all(tmax <= m_ln + 8.f);   // defer-max (log2 units)
        float alpha = 1.f;
        if (!skip){
            const float newm = fmaxf(m_ln, tmax);
            alpha = exp2f(m_ln - newm);
            m_ln = newm;
        }
        float rs = 0.f;
        #pragma unroll
        for (int i = 0; i < 16; ++i){ sv[i] = exp2f(sv[i] - m_ln); rs += sv[i]; }
        rs += __shfl_xor(rs, 16);
        rs += __shfl_xor(rs, 32);
        l_ln = l_ln * alpha + rs;
        if (!skip){
            #pragma unroll
            for (int r = 0; r < 4; ++r){
                const float ar = __shfl(alpha, 4 * g + r);
                #pragma unroll
                for (int nf = 0; nf < 4; ++nf) acc_o[nf][r] *= ar;
            }
        }

        #pragma unroll
        for (int kf = 0; kf < 4; ++kf){
            f16x4 pk = { (f16)sv[kf*4+0], (f16)sv[kf*4+1], (f16)sv[kf*4+2], (f16)sv[kf*4+3] };
            *(f16x4*)(pbase + ((kf * 32 + 8 * g) ^ swp)) = pk;
        }
        __builtin_amdgcn_wave_barrier();

        #pragma unroll
        for (int f = 0; f < 2; ++f){
            f16x8 ap = *(const f16x8*)(pbase + ((f * 64 + 16 * g) ^ swp));
            #pragma unroll
            for (int nf = 0; nf < 4; ++nf){
                const int d = nf * 16 + qq;
                f16x8 bv = *(const f16x8*)(sV[cur] + d * 128 + ((f * 64 + 16 * g) ^ ((d & 7) << 4)));
                acc_o[nf] = mfma16(ap, bv, acc_o[nf]);
            }
        }
        __builtin_amdgcn_wave_barrier();

        if (pre){
            const int nb = cur ^ 1;
            *(f16x8*)(sK[nb] + srow * 128 + swka) = ka;
            *(f16x8*)(sK[nb] + srow * 128 + swkb) = kb2;
            *(f16x8*)(sV[nb] + srow * 128 + swka) = va;
            *(f16x8*)(sV[nb] + srow * 128 + swkb) = vb;
        }
        __syncthreads();
    }

    const float invl = 1.f / l_ln;
    #pragma unroll
    for (int r = 0; r < 4; ++r){
        const float ir = __shfl(invl, 4 * g + r);
        const int row = q0w + 4 * g + r;
        #pragma unroll
        for (int nf = 0; nf < 4; ++nf)
            y[((size_t)(b * 2048 + row)) * 1024 + h * 64 + nf * 16 + qq] = (f16)(acc_o[nf][r] * ir);
    }
}

extern "C" void kernel_launch(void* const* d_in, const int* in_sizes, int n_in,
                              void* d_out, int out_size, void* d_ws, size_t ws_size,
                              hipStream_t stream){
    const float* x  = (const float*)d_in[0];
    const int*   am = (const int*)d_in[1];
    const float* Wq = (const float*)d_in[2];
    const float* Wk = (const float*)d_in[3];
    const float* Wv = (const float*)d_in[4];
    const float* Wp = (const float*)d_in[5];
    float* out = (float*)d_out;

    char* ws = (char*)d_ws;
    const size_t XE = (size_t)4096 * 1024;
    const size_t WE = (size_t)1024 * 1024;

    f16* x16 = (f16*)(ws);
    f16* w16 = (f16*)(ws + XE * 2);
    f16* qkv = (f16*)(ws + XE * 2 + WE * 8);
    f16* vt  = (f16*)(ws + XE * 2 + WE * 8 + XE * 6);
    f16* y16 = (f16*)(ws + XE * 2 + WE * 8 + XE * 8);

    cvt5<<<8192, 256, 0, stream>>>(x, Wq, Wk, Wv, Wp, x16,
                                   (int)(XE / 4), (int)(WE / 4));

    gemm_xwt<f16><<<dim3(8, 32, 3), 256, 0, stream>>>(x16, w16, WE, qkv, XE, 4096, 1024, 1024);

    transpose_v<<<dim3(32, 32), 256, 0, stream>>>(qkv + 2 * XE, vt);

    attn_fused<<<dim3(1024), 256, 0, stream>>>(qkv, qkv + XE, vt, am, y16);

    gemm_xwt<float><<<dim3(8, 32, 1), 256, 0, stream>>>(y16, w16 + 3 * WE, 0, out, 0, 4096, 1024, 1024);
}

// Round 8
// 114.079 us; speedup vs baseline: 1.9749x; 1.1101x over previous
//
#include <hip/hip_runtime.h>
#include <hip/hip_bf16.h>
#include <cstdint>

typedef _Float16 f16;
typedef _Float16 f16x4 __attribute__((ext_vector_type(4)));
typedef _Float16 f16x8 __attribute__((ext_vector_type(8)));
typedef float f32x4 __attribute__((ext_vector_type(4)));

#define LNEG (-1e30f)
#define EXP2(x) __builtin_amdgcn_exp2f(x)   // bare v_exp_f32 (exp2f w/o fast-math is ocml)

__device__ __forceinline__ f32x4 mfma16(f16x8 a, f16x8 b, f32x4 c){
    return __builtin_amdgcn_mfma_f32_16x16x32_f16(a, b, c, 0, 0, 0);
}

// ---------- fused f32 -> f16 convert for x + 4 weights (contiguous dst) ----------
__global__ __launch_bounds__(256) void cvt5(
    const float* __restrict__ x,  const float* __restrict__ wq,
    const float* __restrict__ wk, const float* __restrict__ wv,
    const float* __restrict__ wp, f16* __restrict__ dst, int nx4, int nw4)
{
    int i = blockIdx.x * blockDim.x + threadIdx.x;
    const float* src; int off;
    if (i < nx4){ src = x; off = i; }
    else {
        int j = i - nx4;
        int s = j >> 18;              // nw4 == 2^18
        off = j & (nw4 - 1);
        src = (s == 0) ? wq : (s == 1) ? wk : (s == 2) ? wv : wp;
    }
    float4 v = ((const float4*)src)[off];
    f16x4 o = { (f16)v.x, (f16)v.y, (f16)v.z, (f16)v.w };
    *(f16x4*)&dst[(size_t)i * 4] = o;
}

// ---------- GEMM: reg-staged, XOR-swizzled LDS, double-buffered, 1 barrier/K-step ----
// out[m][n] = sum_k A[m][k]*W[n][k]. For blockIdx.z==2 with vtout!=null the
// epilogue writes V TRANSPOSED (B*H,64,L) directly: each thread's 4 acc rows
// are consecutive l -> contiguous f16x4 store. Kills the transpose kernel.
template<typename OutT>
__global__ __launch_bounds__(256) void gemm_xwt(
    const f16* __restrict__ A, const f16* __restrict__ W0, size_t wstride,
    OutT* __restrict__ out0, size_t ostride, f16* __restrict__ vtout,
    int M, int N, int K)
{
    const int tid  = threadIdx.x;
    const int lane = tid & 63;
    const int w    = tid >> 6;
    const int wr   = w >> 1, wc = w & 1;
    const int m0   = blockIdx.y * 128;
    const int n0   = blockIdx.x * 128;
    const f16* Wz  = W0 + wstride * blockIdx.z;
    OutT* out      = out0 + ostride * blockIdx.z;

    __shared__ f16 At[2][128 * 64];
    __shared__ f16 Bt[2][128 * 64];

    f32x4 acc[4][4] = {};
    f16x8 avr[4], bvr[4];

    int srow[4], scolb[4], sswz[4];
    #pragma unroll
    for (int j = 0; j < 4; ++j){
        int off  = (j * 256 + tid) * 16;
        srow[j]  = off >> 7;
        scolb[j] = off & 127;
        sswz[j]  = srow[j] * 128 + (scolb[j] ^ ((srow[j] & 7) << 4));
    }

    #pragma unroll
    for (int j = 0; j < 4; ++j){
        avr[j] = *(const f16x8*)&A [(size_t)(m0 + srow[j]) * K + (scolb[j] >> 1)];
        bvr[j] = *(const f16x8*)&Wz[(size_t)(n0 + srow[j]) * K + (scolb[j] >> 1)];
    }
    #pragma unroll
    for (int j = 0; j < 4; ++j){
        *(f16x8*)((char*)At[0] + sswz[j]) = avr[j];
        *(f16x8*)((char*)Bt[0] + sswz[j]) = bvr[j];
    }
    __syncthreads();

    const int NT = K >> 6;
    for (int t = 0; t < NT; ++t){
        const int cur = t & 1;
        const bool pre = (t + 1 < NT);
        if (pre){
            const int k0 = (t + 1) << 6;
            #pragma unroll
            for (int j = 0; j < 4; ++j){
                avr[j] = *(const f16x8*)&A [(size_t)(m0 + srow[j]) * K + k0 + (scolb[j] >> 1)];
                bvr[j] = *(const f16x8*)&Wz[(size_t)(n0 + srow[j]) * K + k0 + (scolb[j] >> 1)];
            }
        }
        #pragma unroll
        for (int kk = 0; kk < 2; ++kk){
            f16x8 af[4], bf[4];
            #pragma unroll
            for (int mf = 0; mf < 4; ++mf){
                int row = wr * 64 + mf * 16 + (lane & 15);
                int cb  = (kk * 64 + 16 * (lane >> 4)) ^ ((row & 7) << 4);
                af[mf] = *(const f16x8*)((const char*)At[cur] + row * 128 + cb);
            }
            #pragma unroll
            for (int nf = 0; nf < 4; ++nf){
                int row = wc * 64 + nf * 16 + (lane & 15);
                int cb  = (kk * 64 + 16 * (lane >> 4)) ^ ((row & 7) << 4);
                bf[nf] = *(const f16x8*)((const char*)Bt[cur] + row * 128 + cb);
            }
            #pragma unroll
            for (int mf = 0; mf < 4; ++mf)
                #pragma unroll
                for (int nf = 0; nf < 4; ++nf)
                    acc[mf][nf] = mfma16(af[mf], bf[nf], acc[mf][nf]);
        }
        if (pre){
            const int nb = cur ^ 1;
            #pragma unroll
            for (int j = 0; j < 4; ++j){
                *(f16x8*)((char*)At[nb] + sswz[j]) = avr[j];
                *(f16x8*)((char*)Bt[nb] + sswz[j]) = bvr[j];
            }
        }
        __syncthreads();
    }

    if (vtout != nullptr && blockIdx.z == 2){
        // V epilogue: write transposed. row=l (4 consecutive), col=h*64+d
        #pragma unroll
        for (int mf = 0; mf < 4; ++mf)
            #pragma unroll
            for (int nf = 0; nf < 4; ++nf){
                int row = m0 + wr * 64 + mf * 16 + 4 * (lane >> 4);
                int col = n0 + wc * 64 + nf * 16 + (lane & 15);
                int bb = row >> 11, ll = row & 2047;
                int bh = bb * 16 + (col >> 6), dd = col & 63;
                f16x4 o = { (f16)acc[mf][nf][0], (f16)acc[mf][nf][1],
                            (f16)acc[mf][nf][2], (f16)acc[mf][nf][3] };
                *(f16x4*)&vtout[((size_t)(bh * 64 + dd)) * 2048 + ll] = o;
            }
    } else {
        #pragma unroll
        for (int mf = 0; mf < 4; ++mf)
            #pragma unroll
            for (int nf = 0; nf < 4; ++nf)
                #pragma unroll
                for (int r = 0; r < 4; ++r){
                    int row = m0 + wr * 64 + mf * 16 + 4 * (lane >> 4) + r;
                    int col = n0 + wc * 64 + nf * 16 + (lane & 15);
                    out[(size_t)row * N + col] = (OutT)acc[mf][nf][r];
                }
    }
}

// ---------- fused causal flash attention (round-2 body; XCD-local remap) ----------
__global__ __launch_bounds__(256, 4) void attn_fused(
    const f16* __restrict__ q, const f16* __restrict__ k,
    const f16* __restrict__ vt, const int* __restrict__ amask,
    f16* __restrict__ y)
{
    const int tid  = threadIdx.x;
    const int lane = tid & 63;
    const int w    = tid >> 6;
    const int g    = lane >> 4;
    const int qq   = lane & 15;

    const int lin = blockIdx.x;
    const int bh  = ((lin & 7) << 2) | ((lin >> 3) & 3);
    const int qtv = (lin >> 5) & 31;
    const int q5  = (qtv & 7) | ((qtv & 16) >> 1);
    const int qt  = (qtv & 8) ? (31 - q5) : q5;
    const int b = bh >> 4, h = bh & 15;
    const int q0w = qt * 64 + w * 16;
    const int nkt = qt + 1;

    __shared__ char sK[2][64 * 128];
    __shared__ char sV[2][64 * 128];
    __shared__ char sP[4][16 * 128];

    const int srow = (tid * 2) >> 3;
    const int sc8a = (tid * 2) & 7, sc8b = sc8a + 1;
    const int swka = (sc8a * 16) ^ ((srow & 7) << 4);
    const int swkb = (sc8b * 16) ^ ((srow & 7) << 4);
    const f16* kbase  = k  + ((size_t)b * 2048) * 1024 + h * 64;
    const f16* vtbase = vt + (size_t)bh * 64 * 2048;

    const f16 qscale = (f16)(0.125f * 1.44269504088896f);
    f16x8 aq[2];
    #pragma unroll
    for (int f = 0; f < 2; ++f){
        aq[f] = *(const f16x8*)&q[((size_t)(b * 2048 + q0w + qq)) * 1024 + h * 64 + f * 32 + 8 * g];
        #pragma unroll
        for (int j = 0; j < 8; ++j) aq[f][j] *= qscale;
    }

    f32x4 acc_o[4] = {};
    float m_ln = LNEG, l_ln = 0.f;

    char* pbase = sP[w] + qq * 128;
    const int swp = (qq & 7) << 4;

    {
        f16x8 ka  = *(const f16x8*)(kbase  + (size_t)srow * 1024 + sc8a * 8);
        f16x8 kb2 = *(const f16x8*)(kbase  + (size_t)srow * 1024 + sc8b * 8);
        f16x8 va  = *(const f16x8*)(vtbase + (size_t)srow * 2048 + sc8a * 8);
        f16x8 vb  = *(const f16x8*)(vtbase + (size_t)srow * 2048 + sc8b * 8);
        *(f16x8*)(sK[0] + srow * 128 + swka) = ka;
        *(f16x8*)(sK[0] + srow * 128 + swkb) = kb2;
        *(f16x8*)(sV[0] + srow * 128 + swka) = va;
        *(f16x8*)(sV[0] + srow * 128 + swkb) = vb;
    }
    __syncthreads();

    for (int kt = 0; kt < nkt; ++kt){
        const int cur = kt & 1;
        const int k0 = kt * 64;
        const bool pre = (kt + 1 < nkt);

        f16x8 ka, kb2, va, vb;
        if (pre){
            const int nk0 = k0 + 64;
            ka  = *(const f16x8*)(kbase  + (size_t)(nk0 + srow) * 1024 + sc8a * 8);
            kb2 = *(const f16x8*)(kbase  + (size_t)(nk0 + srow) * 1024 + sc8b * 8);
            va  = *(const f16x8*)(vtbase + (size_t)srow * 2048 + nk0 + sc8a * 8);
            vb  = *(const f16x8*)(vtbase + (size_t)srow * 2048 + nk0 + sc8b * 8);
        }

        unsigned long long tokbits = __ballot(amask[b * 2048 + k0 + lane] != 0);
        const bool tokall = (tokbits == ~0ull);

        f32x4 acc_s[4] = {};
        #pragma unroll
        for (int kf = 0; kf < 4; ++kf){
            const int keyl = kf * 16 + qq;
            const char* kr = sK[cur] + keyl * 128;
            const int sw = (keyl & 7) << 4;
            #pragma unroll
            for (int f = 0; f < 2; ++f){
                f16x8 ak = *(const f16x8*)(kr + ((f * 64 + 16 * g) ^ sw));
                acc_s[kf] = mfma16(ak, aq[f], acc_s[kf]);
            }
        }

        const bool fullt = (k0 + 63 <= q0w) && tokall;
        float sv[16];
        #pragma unroll
        for (int kf = 0; kf < 4; ++kf)
            #pragma unroll
            for (int r = 0; r < 4; ++r){
                float s = acc_s[kf][r];
                if (!fullt){
                    const int keyl = kf * 16 + 4 * g + r;
                    const bool ok = (k0 + keyl <= q0w + qq) && ((tokbits >> keyl) & 1);
                    s = ok ? s : LNEG;
                }
                sv[kf * 4 + r] = s;
            }

        float tmax = sv[0];
        #pragma unroll
        for (int i = 1; i < 16; ++i) tmax = fmaxf(tmax, sv[i]);
        tmax = fmaxf(tmax, __shfl_xor(tmax, 16));
        tmax = fmaxf(tmax, __shfl_xor(tmax, 32));
        const bool skip = __all(tmax <= m_ln + 8.f);   // defer-max (log2 units)
        float alpha = 1.f;
        if (!skip){
            const float newm = fmaxf(m_ln, tmax);
            alpha = EXP2(m_ln - newm);
            m_ln = newm;
        }
        float rs = 0.f;
        #pragma unroll
        for (int i = 0; i < 16; ++i){ sv[i] = EXP2(sv[i] - m_ln); rs += sv[i]; }
        rs += __shfl_xor(rs, 16);
        rs += __shfl_xor(rs, 32);
        l_ln = l_ln * alpha + rs;
        if (!skip){
            #pragma unroll
            for (int r = 0; r < 4; ++r){
                const float ar = __shfl(alpha, 4 * g + r);
                #pragma unroll
                for (int nf = 0; nf < 4; ++nf) acc_o[nf][r] *= ar;
            }
        }

        #pragma unroll
        for (int kf = 0; kf < 4; ++kf){
            f16x4 pk = { (f16)sv[kf*4+0], (f16)sv[kf*4+1], (f16)sv[kf*4+2], (f16)sv[kf*4+3] };
            *(f16x4*)(pbase + ((kf * 32 + 8 * g) ^ swp)) = pk;
        }
        __builtin_amdgcn_wave_barrier();

        #pragma unroll
        for (int f = 0; f < 2; ++f){
            f16x8 ap = *(const f16x8*)(pbase + ((f * 64 + 16 * g) ^ swp));
            #pragma unroll
            for (int nf = 0; nf < 4; ++nf){
                const int d = nf * 16 + qq;
                f16x8 bv = *(const f16x8*)(sV[cur] + d * 128 + ((f * 64 + 16 * g) ^ ((d & 7) << 4)));
                acc_o[nf] = mfma16(ap, bv, acc_o[nf]);
            }
        }
        __builtin_amdgcn_wave_barrier();

        if (pre){
            const int nb = cur ^ 1;
            *(f16x8*)(sK[nb] + srow * 128 + swka) = ka;
            *(f16x8*)(sK[nb] + srow * 128 + swkb) = kb2;
            *(f16x8*)(sV[nb] + srow * 128 + swka) = va;
            *(f16x8*)(sV[nb] + srow * 128 + swkb) = vb;
        }
        __syncthreads();
    }

    const float invl = 1.f / l_ln;
    #pragma unroll
    for (int r = 0; r < 4; ++r){
        const float ir = __shfl(invl, 4 * g + r);
        const int row = q0w + 4 * g + r;
        #pragma unroll
        for (int nf = 0; nf < 4; ++nf)
            y[((size_t)(b * 2048 + row)) * 1024 + h * 64 + nf * 16 + qq] = (f16)(acc_o[nf][r] * ir);
    }
}

extern "C" void kernel_launch(void* const* d_in, const int* in_sizes, int n_in,
                              void* d_out, int out_size, void* d_ws, size_t ws_size,
                              hipStream_t stream){
    const float* x  = (const float*)d_in[0];
    const int*   am = (const int*)d_in[1];
    const float* Wq = (const float*)d_in[2];
    const float* Wk = (const float*)d_in[3];
    const float* Wv = (const float*)d_in[4];
    const float* Wp = (const float*)d_in[5];
    float* out = (float*)d_out;

    char* ws = (char*)d_ws;
    const size_t XE = (size_t)4096 * 1024;
    const size_t WE = (size_t)1024 * 1024;

    f16* x16 = (f16*)(ws);
    f16* w16 = (f16*)(ws + XE * 2);
    f16* qkv = (f16*)(ws + XE * 2 + WE * 8);
    f16* vt  = (f16*)(ws + XE * 2 + WE * 8 + XE * 6);
    f16* y16 = (f16*)(ws + XE * 2 + WE * 8 + XE * 8);

    cvt5<<<8192, 256, 0, stream>>>(x, Wq, Wk, Wv, Wp, x16,
                                   (int)(XE / 4), (int)(WE / 4));

    // z=0,1 -> q,k normal layout; z=2 -> V written TRANSPOSED into vt
    gemm_xwt<f16><<<dim3(8, 32, 3), 256, 0, stream>>>(x16, w16, WE, qkv, XE, vt, 4096, 1024, 1024);

    attn_fused<<<dim3(1024), 256, 0, stream>>>(qkv, qkv + XE, vt, am, y16);

    gemm_xwt<float><<<dim3(8, 32, 1), 256, 0, stream>>>(y16, w16 + 3 * WE, 0, out, 0, nullptr, 4096, 1024, 1024);
}